// Round 2
// baseline (421.439 us; speedup 1.0000x reference)
//
#include <hip/hip_runtime.h>

#define HH 192
#define WW 192
#define CC 16
#define HW (HH * WW)
#define TH 30
#define TW 24
#define RS 44               // plane row stride in floats = 11 float4 chunks
#define PCHUNKS 512         // chunks per plane buffer = 256 threads x 2 (ALL DMA'd)
#define PLANEF (PCHUNKS*4)  // 2048 floats per buffer
#define RSS 28              // rowsum row stride floats
#define SMEMF (9 * 32 * RSS)  // 8064 floats = 32256 B (>= 2*PLANEF = 4096 floats)

// 16B of guaranteed zeros in global memory: OOB lanes DMA from here so the
// global_load_lds is exec-uniform (lane 0 always active -> correct wave base).
__device__ float g_zero16[4] = {0.f, 0.f, 0.f, 0.f};

__device__ __forceinline__ void gload16(const void* g, void* l) {
    __builtin_amdgcn_global_load_lds(
        (const __attribute__((address_space(1))) void*)g,
        (__attribute__((address_space(3))) void*)l, 16, 0, 0);
}

// Block: 256 threads = 32 corr-rows x 8 col-groups(4 cols).
// Each block: one batch, one 30x24 EXTENDED tile (ye=-4+30*by, xe=-4+24*bx),
// one oy-group: grp0 -> oy {-4,-3,-2}, grp1 -> oy {-1,0}.
// Symmetry: out_{-o}(y+oy, x+ox) = out_o(y,x) => mirror-write oy>0 planes.
// LDS: single 31.5 KB buffer, time-aliased:
//   main loop  -> planes[2*PLANEF] (16 KB double-buffered DMA dest)
//   epilogue   -> rsum[9*32*RSS]   (31.5 KB)
// 31.5 KB/block -> 5 blocks/CU (vs 3 before) -> whole 1008-block grid resident
// in one round (capacity 1280), 20 waves/CU.
__global__ __launch_bounds__(256, 5)
void noise_corr_kernel(const float* __restrict__ noise, float* __restrict__ out) {
    __shared__ float smem[SMEMF];
    float* const planes = smem;            // alias: valid until last channel compute
    float* const rsum   = smem;            // alias: valid after epilogue barrier

    const int tid = threadIdx.x;
    const int r   = tid >> 3;          // 0..31 -> corr row yy = r-1
    const int g   = tid & 7;           // 0..7  -> cols xs = 4g-4
    const int bx  = blockIdx.x % 9;
    const int by  = blockIdx.x / 9;
    const int grp = blockIdx.y;
    const int b   = blockIdx.z;

    const int oymin = grp ? -1 : -4;
    const int NOY   = grp ? 2 : 3;
    const int rmin  = oymin - 1;
    const int NR    = TH + 2 - oymin;  // 36 (grp0) / 33 (grp1)
    const int nitems = NR * 11;        // used float4 chunks (<= 512)

    const int y0 = -4 + by * TH;       // extended tile origin
    const int x0 = -4 + bx * TW;
    const int yy = r - 1;
    const int xs = (g << 2) - 4;

    const float* nb = noise + (size_t)b * CC * HW;
    const char* zp = (const char*)g_zero16;

    // precompute this thread's 2 staging chunks (plane offset = 16*i, linear in tid)
    int goff[2]; bool gok[2];
    #pragma unroll
    for (int k = 0; k < 2; ++k) {
        const int i  = tid + (k << 8);
        const int rr = i / 11;
        const int q  = i - rr * 11;
        const int gy = y0 + rmin + rr;
        const int gx = x0 - 8 + (q << 2);   // 4-aligned -> chunk fully in or out
        gok[k]  = (i < nitems) && ((unsigned)gy < HH) && ((unsigned)gx <= (WW - 4));
        goff[k] = (gy * WW + gx) * 4;
    }

    float acc[3][9][4];
    #pragma unroll
    for (int t = 0; t < 3; ++t)
        #pragma unroll
        for (int o = 0; o < 9; ++o) {
            acc[t][o][0] = 0.f; acc[t][o][1] = 0.f;
            acc[t][o][2] = 0.f; acc[t][o][3] = 0.f;
        }

    // stage channel 0 -> buffer 0 (unconditional: OOB lanes fetch zeros)
    {
        const char* base = (const char*)nb;
        char* lb = (char*)planes;
        gload16(gok[0] ? base + goff[0] : zp, lb + (tid << 4));
        gload16(gok[1] ? base + goff[1] : zp, lb + ((tid + 256) << 4));
    }

    const int ci = yy - rmin;   // center row in plane; shifted row = ci + oy

    for (int c = 0; c < CC; ++c) {
        __syncthreads();   // drains DMA for channel c (vmcnt(0) before s_barrier)
        if (c + 1 < CC) {
            const char* base = (const char*)(nb + (size_t)(c + 1) * HW);
            char* lb = (char*)planes + ((c + 1) & 1) * (PLANEF * 4);
            gload16(gok[0] ? base + goff[0] : zp, lb + (tid << 4));
            gload16(gok[1] ? base + goff[1] : zp, lb + ((tid + 256) << 4));
        }
        const float* pl = planes + (c & 1) * PLANEF;
        const float4 cen4 = *(const float4*)&pl[ci * RS + xs + 8];
        const float cen[4] = {cen4.x, cen4.y, cen4.z, cen4.w};
        #pragma unroll
        for (int t = 0; t < 3; ++t) {
            if (t < NOY) {
                const float* sr = &pl[(ci + oymin + t) * RS + xs + 4];
                float sh[12];
                *(float4*)&sh[0] = *(const float4*)&sr[0];
                *(float4*)&sh[4] = *(const float4*)&sr[4];
                *(float4*)&sh[8] = *(const float4*)&sr[8];
                #pragma unroll
                for (int o = 0; o < 9; ++o)
                    #pragma unroll
                    for (int j = 0; j < 4; ++j)
                        acc[t][o][j] += cen[j] * sh[o + j];
            }
        }
    }

    // epilogue: per oy -> rowsum (shfl + LDS), colsum, direct + mirror stores
    const float inv = 1.0f / 144.0f;
    float* outb = out + (size_t)b * 81 * HW;
    const int yb  = tid / 6;    // colsum mapping (tid<180): y 0..29
    const int xgb = tid % 6;    // x-group 0..5 (float4)

    #pragma unroll
    for (int t = 0; t < 3; ++t) {
        if (t < NOY) {
            const int oy = oymin + t;
            // unconditional: at t=0 this fences last planes-read vs rsum-write
            // (planes and rsum alias); at t>0 it fences previous colsum reads.
            __syncthreads();
            #pragma unroll
            for (int o = 0; o < 9; ++o) {
                const float a0 = acc[t][o][0], a1 = acc[t][o][1];
                const float a2 = acc[t][o][2], a3 = acc[t][o][3];
                const float left  = __shfl_up(a3, 1);    // (r,g-1) corr at xs-1
                const float right = __shfl_down(a0, 1);  // (r,g+1) corr at xs+4
                if (g >= 1 && g <= 6) {
                    float4 v;
                    v.x = left + a0 + a1;
                    v.y = a0 + a1 + a2;
                    v.z = a1 + a2 + a3;
                    v.w = a2 + a3 + right;
                    *(float4*)&rsum[(o * 32 + r) * RSS + ((g - 1) << 2)] = v;
                }
            }
            __syncthreads();
            if (tid < 180) {
                const int gy = y0 + yb;
                const int gx = x0 + (xgb << 2);
                const bool dok = ((unsigned)gy < HH) && ((unsigned)gx <= (WW - 4));
                const int my = gy + oy;
                #pragma unroll
                for (int o = 0; o < 9; ++o) {
                    const float* rp = &rsum[(o * 32 + yb) * RSS + (xgb << 2)];
                    const float4 s0 = *(const float4*)&rp[0];
                    const float4 s1 = *(const float4*)&rp[RSS];
                    const float4 s2 = *(const float4*)&rp[2 * RSS];
                    float4 s;
                    s.x = (s0.x + s1.x + s2.x) * inv;
                    s.y = (s0.y + s1.y + s2.y) * inv;
                    s.z = (s0.z + s1.z + s2.z) * inv;
                    s.w = (s0.w + s1.w + s2.w) * inv;
                    if (dok)
                        *(float4*)&outb[((size_t)((oy + 4) * 9 + o)) * HW + gy * WW + gx] = s;
                    if (oy < 0 && (unsigned)my < HH) {
                        // mirror: out_{(-oy,-ox)}(gy+oy, gx+j+ox) = s[j]
                        float* mp = &outb[((size_t)((4 - oy) * 9 + (8 - o))) * HW + (size_t)my * WW];
                        const float sv[4] = {s.x, s.y, s.z, s.w};
                        const int mx0 = gx + (o - 4);
                        #pragma unroll
                        for (int j = 0; j < 4; ++j) {
                            const int mx = mx0 + j;
                            if ((unsigned)mx < WW) mp[mx] = sv[j];
                        }
                    }
                }
            }
        }
    }
}

extern "C" void kernel_launch(void* const* d_in, const int* in_sizes, int n_in,
                              void* d_out, int out_size, void* d_ws, size_t ws_size,
                              hipStream_t stream) {
    const float* noise = (const float*)d_in[0];
    float* out = (float*)d_out;
    dim3 grid(9 * 7, 2, 8);   // 9 bx x 7 by extended tiles, 2 oy-groups, 8 batches
    noise_corr_kernel<<<grid, 256, 0, stream>>>(noise, out);
}

// Round 3
// 274.152 us; speedup vs baseline: 1.5372x; 1.5372x over previous
//
#include <hip/hip_runtime.h>

#define HH 192
#define WW 192
#define CC 16
#define HW (HH * WW)
#define TH 30
#define TW 24
#define RS 44               // plane row stride in floats = 11 float4 chunks
#define PCHUNKS 512         // chunks per plane buffer = 256 threads x 2 (ALL DMA'd)
#define PLANEF (PCHUNKS*4)  // 2048 floats per buffer
#define RSS 28              // rowsum row stride floats
#define SMEMF (9 * 32 * RSS)  // 8064 floats = 32256 B (>= 2*PLANEF = 4096 floats)

// 16B of guaranteed zeros in global memory: OOB lanes DMA from here so the
// global_load_lds is exec-uniform (lane 0 always active -> correct wave base).
__device__ float g_zero16[4] = {0.f, 0.f, 0.f, 0.f};

__device__ __forceinline__ void gload16(const void* g, void* l) {
    __builtin_amdgcn_global_load_lds(
        (const __attribute__((address_space(1))) void*)g,
        (__attribute__((address_space(3))) void*)l, 16, 0, 0);
}

// Block: 256 threads = 32 corr-rows x 8 col-groups(4 cols).
// Each block: one batch, one 30x24 EXTENDED tile (ye=-4+30*by, xe=-4+24*bx),
// one oy-group: grp0 -> oy {-4,-3,-2}, grp1 -> oy {-1,0}.
// Symmetry: out_{-o}(y+oy, x+ox) = out_o(y,x) => mirror-write oy>0 planes.
// LDS: single 31.5 KB buffer, time-aliased:
//   main loop  -> planes[2*PLANEF] (16 KB double-buffered DMA dest)
//   epilogue   -> rsum[9*32*RSS]   (31.5 KB)
// Occupancy: launch_bounds(256,4) -> 128-reg cap (acc[3][9][4]=108 live floats
// fits; (256,5)'s ~96-reg cap spilled acc to scratch -> 1.25 GB HBM, 2.6x slower).
// 4 blocks/CU x 256 CU = 1024 >= 1008-block grid -> single-round dispatch.
__global__ __launch_bounds__(256, 4)
void noise_corr_kernel(const float* __restrict__ noise, float* __restrict__ out) {
    __shared__ float smem[SMEMF];
    float* const planes = smem;            // alias: valid until last channel compute
    float* const rsum   = smem;            // alias: valid after epilogue barrier

    const int tid = threadIdx.x;
    const int r   = tid >> 3;          // 0..31 -> corr row yy = r-1
    const int g   = tid & 7;           // 0..7  -> cols xs = 4g-4
    const int bx  = blockIdx.x % 9;
    const int by  = blockIdx.x / 9;
    const int grp = blockIdx.y;
    const int b   = blockIdx.z;

    const int oymin = grp ? -1 : -4;
    const int NOY   = grp ? 2 : 3;
    const int rmin  = oymin - 1;
    const int NR    = TH + 2 - oymin;  // 36 (grp0) / 33 (grp1)
    const int nitems = NR * 11;        // used float4 chunks (<= 512)

    const int y0 = -4 + by * TH;       // extended tile origin
    const int x0 = -4 + bx * TW;
    const int yy = r - 1;
    const int xs = (g << 2) - 4;

    const float* nb = noise + (size_t)b * CC * HW;
    const char* zp = (const char*)g_zero16;

    // precompute this thread's 2 staging chunks (plane offset = 16*i, linear in tid)
    int goff[2]; bool gok[2];
    #pragma unroll
    for (int k = 0; k < 2; ++k) {
        const int i  = tid + (k << 8);
        const int rr = i / 11;
        const int q  = i - rr * 11;
        const int gy = y0 + rmin + rr;
        const int gx = x0 - 8 + (q << 2);   // 4-aligned -> chunk fully in or out
        gok[k]  = (i < nitems) && ((unsigned)gy < HH) && ((unsigned)gx <= (WW - 4));
        goff[k] = (gy * WW + gx) * 4;
    }

    float acc[3][9][4];
    #pragma unroll
    for (int t = 0; t < 3; ++t)
        #pragma unroll
        for (int o = 0; o < 9; ++o) {
            acc[t][o][0] = 0.f; acc[t][o][1] = 0.f;
            acc[t][o][2] = 0.f; acc[t][o][3] = 0.f;
        }

    // stage channel 0 -> buffer 0 (unconditional: OOB lanes fetch zeros)
    {
        const char* base = (const char*)nb;
        char* lb = (char*)planes;
        gload16(gok[0] ? base + goff[0] : zp, lb + (tid << 4));
        gload16(gok[1] ? base + goff[1] : zp, lb + ((tid + 256) << 4));
    }

    const int ci = yy - rmin;   // center row in plane; shifted row = ci + oy

    for (int c = 0; c < CC; ++c) {
        __syncthreads();   // drains DMA for channel c (vmcnt(0) before s_barrier)
        if (c + 1 < CC) {
            const char* base = (const char*)(nb + (size_t)(c + 1) * HW);
            char* lb = (char*)planes + ((c + 1) & 1) * (PLANEF * 4);
            gload16(gok[0] ? base + goff[0] : zp, lb + (tid << 4));
            gload16(gok[1] ? base + goff[1] : zp, lb + ((tid + 256) << 4));
        }
        const float* pl = planes + (c & 1) * PLANEF;
        const float4 cen4 = *(const float4*)&pl[ci * RS + xs + 8];
        const float cen[4] = {cen4.x, cen4.y, cen4.z, cen4.w};
        #pragma unroll
        for (int t = 0; t < 3; ++t) {
            if (t < NOY) {
                const float* sr = &pl[(ci + oymin + t) * RS + xs + 4];
                float sh[12];
                *(float4*)&sh[0] = *(const float4*)&sr[0];
                *(float4*)&sh[4] = *(const float4*)&sr[4];
                *(float4*)&sh[8] = *(const float4*)&sr[8];
                #pragma unroll
                for (int o = 0; o < 9; ++o)
                    #pragma unroll
                    for (int j = 0; j < 4; ++j)
                        acc[t][o][j] += cen[j] * sh[o + j];
            }
        }
    }

    // epilogue: per oy -> rowsum (shfl + LDS), colsum, direct + mirror stores
    const float inv = 1.0f / 144.0f;
    float* outb = out + (size_t)b * 81 * HW;
    const int yb  = tid / 6;    // colsum mapping (tid<180): y 0..29
    const int xgb = tid % 6;    // x-group 0..5 (float4)

    #pragma unroll
    for (int t = 0; t < 3; ++t) {
        if (t < NOY) {
            const int oy = oymin + t;
            // unconditional: at t=0 this fences last planes-read vs rsum-write
            // (planes and rsum alias); at t>0 it fences previous colsum reads.
            __syncthreads();
            #pragma unroll
            for (int o = 0; o < 9; ++o) {
                const float a0 = acc[t][o][0], a1 = acc[t][o][1];
                const float a2 = acc[t][o][2], a3 = acc[t][o][3];
                const float left  = __shfl_up(a3, 1);    // (r,g-1) corr at xs-1
                const float right = __shfl_down(a0, 1);  // (r,g+1) corr at xs+4
                if (g >= 1 && g <= 6) {
                    float4 v;
                    v.x = left + a0 + a1;
                    v.y = a0 + a1 + a2;
                    v.z = a1 + a2 + a3;
                    v.w = a2 + a3 + right;
                    *(float4*)&rsum[(o * 32 + r) * RSS + ((g - 1) << 2)] = v;
                }
            }
            __syncthreads();
            if (tid < 180) {
                const int gy = y0 + yb;
                const int gx = x0 + (xgb << 2);
                const bool dok = ((unsigned)gy < HH) && ((unsigned)gx <= (WW - 4));
                const int my = gy + oy;
                #pragma unroll
                for (int o = 0; o < 9; ++o) {
                    const float* rp = &rsum[(o * 32 + yb) * RSS + (xgb << 2)];
                    const float4 s0 = *(const float4*)&rp[0];
                    const float4 s1 = *(const float4*)&rp[RSS];
                    const float4 s2 = *(const float4*)&rp[2 * RSS];
                    float4 s;
                    s.x = (s0.x + s1.x + s2.x) * inv;
                    s.y = (s0.y + s1.y + s2.y) * inv;
                    s.z = (s0.z + s1.z + s2.z) * inv;
                    s.w = (s0.w + s1.w + s2.w) * inv;
                    if (dok)
                        *(float4*)&outb[((size_t)((oy + 4) * 9 + o)) * HW + gy * WW + gx] = s;
                    if (oy < 0 && (unsigned)my < HH) {
                        // mirror: out_{(-oy,-ox)}(gy+oy, gx+j+ox) = s[j]
                        float* mp = &outb[((size_t)((4 - oy) * 9 + (8 - o))) * HW + (size_t)my * WW];
                        const float sv[4] = {s.x, s.y, s.z, s.w};
                        const int mx0 = gx + (o - 4);
                        #pragma unroll
                        for (int j = 0; j < 4; ++j) {
                            const int mx = mx0 + j;
                            if ((unsigned)mx < WW) mp[mx] = sv[j];
                        }
                    }
                }
            }
        }
    }
}

extern "C" void kernel_launch(void* const* d_in, const int* in_sizes, int n_in,
                              void* d_out, int out_size, void* d_ws, size_t ws_size,
                              hipStream_t stream) {
    const float* noise = (const float*)d_in[0];
    float* out = (float*)d_out;
    dim3 grid(9 * 7, 2, 8);   // 9 bx x 7 by extended tiles, 2 oy-groups, 8 batches
    noise_corr_kernel<<<grid, 256, 0, stream>>>(noise, out);
}

// Round 4
// 176.253 us; speedup vs baseline: 2.3911x; 1.5554x over previous
//
#include <hip/hip_runtime.h>

#define HH 192
#define WW 192
#define CC 16
#define HW (HH * WW)
#define TH 30
#define TW 24
#define RS 44               // plane row stride in floats = 11 float4 chunks
#define PCHUNKS 512         // chunks per plane buffer = 256 threads x 2 (ALL DMA'd)
#define PLANEF (PCHUNKS*4)  // 2048 floats per buffer
#define RSS 28              // rowsum row stride floats
#define SMEMF (9 * 32 * RSS)  // 8064 floats = 32256 B (>= 3*PLANEF = 6144 floats)

// 16B of guaranteed zeros in global memory: OOB lanes DMA from here so the
// global_load_lds is exec-uniform (lane 0 always active -> correct wave base).
__device__ float g_zero16[4] = {0.f, 0.f, 0.f, 0.f};

__device__ __forceinline__ void gload16(const void* g, void* l) {
    __builtin_amdgcn_global_load_lds(
        (const __attribute__((address_space(1))) void*)g,
        (__attribute__((address_space(3))) void*)l, 16, 0, 0);
}

// Block: 256 threads = 32 corr-rows x 8 col-groups(4 cols).
// Each block: one batch, one 30x24 EXTENDED tile, one oy-group
// (grp0 -> oy {-4,-3,-2}, grp1 -> oy {-1,0}); mirror-write oy>0 planes.
//
// launch_bounds MUST stay (256,3): empirical VGPR cap on this toolchain is
// 256/w (w=3 -> 84 regs, no spill; w=4 -> 64 regs, 300 MB scratch, 2x slower;
// w=5 -> 48 regs, 1.1 GB scratch, 3.4x slower). acc[3][9][4] needs w=3.
//
// DMA pipeline (T3/T4-lite): TRIPLE-buffered global_load_lds with raw
// s_barrier + counted s_waitcnt vmcnt(2) -- never vmcnt(0) in steady state.
// __syncthreads() would emit vmcnt(0) before s_barrier and drain the whole
// queue every channel (the round-0 ~70% latency stall). Prefetch distance = 2
// channels (~1500+ cyc of compute cover vs ~600-900 cyc DMA latency).
//
// LDS: single 31.5 KB buffer, time-aliased:
//   main loop -> planes[3*PLANEF] (24 KB triple-buffered DMA dest)
//   epilogue  -> rsum[9*32*RSS]   (31.5 KB)
__global__ __launch_bounds__(256, 3)
void noise_corr_kernel(const float* __restrict__ noise, float* __restrict__ out) {
    __shared__ float smem[SMEMF];
    float* const planes = smem;            // alias: valid until last channel compute
    float* const rsum   = smem;            // alias: valid after epilogue barrier

    const int tid = threadIdx.x;
    const int r   = tid >> 3;          // 0..31 -> corr row yy = r-1
    const int g   = tid & 7;           // 0..7  -> cols xs = 4g-4
    const int bx  = blockIdx.x % 9;
    const int by  = blockIdx.x / 9;
    const int grp = blockIdx.y;
    const int b   = blockIdx.z;

    const int oymin = grp ? -1 : -4;
    const int NOY   = grp ? 2 : 3;
    const int rmin  = oymin - 1;
    const int NR    = TH + 2 - oymin;  // 36 (grp0) / 33 (grp1)
    const int nitems = NR * 11;        // used float4 chunks (<= 512)

    const int y0 = -4 + by * TH;       // extended tile origin
    const int x0 = -4 + bx * TW;
    const int yy = r - 1;
    const int xs = (g << 2) - 4;

    const float* nb = noise + (size_t)b * CC * HW;
    const char* zp = (const char*)g_zero16;

    // precompute this thread's 2 staging chunks (plane offset = 16*i, linear in tid)
    int goff[2]; bool gok[2];
    #pragma unroll
    for (int k = 0; k < 2; ++k) {
        const int i  = tid + (k << 8);
        const int rr = i / 11;
        const int q  = i - rr * 11;
        const int gy = y0 + rmin + rr;
        const int gx = x0 - 8 + (q << 2);   // 4-aligned -> chunk fully in or out
        gok[k]  = (i < nitems) && ((unsigned)gy < HH) && ((unsigned)gx <= (WW - 4));
        goff[k] = (gy * WW + gx) * 4;
    }

    float acc[3][9][4];
    #pragma unroll
    for (int t = 0; t < 3; ++t)
        #pragma unroll
        for (int o = 0; o < 9; ++o) {
            acc[t][o][0] = 0.f; acc[t][o][1] = 0.f;
            acc[t][o][2] = 0.f; acc[t][o][3] = 0.f;
        }

    // prologue: stage channels 0 and 1 into slots 0 and 1 (4 loads in flight)
    {
        const char* base0 = (const char*)nb;
        const char* base1 = (const char*)(nb + (size_t)HW);
        char* lb0 = (char*)planes;
        char* lb1 = (char*)planes + PLANEF * 4;
        gload16(gok[0] ? base0 + goff[0] : zp, lb0 + (tid << 4));
        gload16(gok[1] ? base0 + goff[1] : zp, lb0 + ((tid + 256) << 4));
        gload16(gok[0] ? base1 + goff[0] : zp, lb1 + (tid << 4));
        gload16(gok[1] ? base1 + goff[1] : zp, lb1 + ((tid + 256) << 4));
    }

    const int ci = yy - rmin;   // center row in plane; shifted row = ci + oy

    for (int c = 0; c < CC; ++c) {
        // wait for THIS wave's slot-c loads only (2 newest stay in flight),
        // then raw barrier (no compiler vmcnt(0) drain).
        if (c == CC - 1) {
            asm volatile("s_waitcnt vmcnt(0)" ::: "memory");
        } else {
            asm volatile("s_waitcnt vmcnt(2)" ::: "memory");
        }
        __builtin_amdgcn_sched_barrier(0);   // rule #18: pin reads below the wait
        __builtin_amdgcn_s_barrier();
        // issue slot c+2: its previous readers (compute c-1) all passed the
        // barrier above, so the DMA write cannot race them.
        if (c + 2 < CC) {
            const char* base = (const char*)(nb + (size_t)(c + 2) * HW);
            char* lb = (char*)planes + ((c + 2) % 3) * (PLANEF * 4);
            gload16(gok[0] ? base + goff[0] : zp, lb + (tid << 4));
            gload16(gok[1] ? base + goff[1] : zp, lb + ((tid + 256) << 4));
        }
        const float* pl = planes + (c % 3) * PLANEF;
        const float4 cen4 = *(const float4*)&pl[ci * RS + xs + 8];
        const float cen[4] = {cen4.x, cen4.y, cen4.z, cen4.w};
        #pragma unroll
        for (int t = 0; t < 3; ++t) {
            if (t < NOY) {
                const float* sr = &pl[(ci + oymin + t) * RS + xs + 4];
                float sh[12];
                *(float4*)&sh[0] = *(const float4*)&sr[0];
                *(float4*)&sh[4] = *(const float4*)&sr[4];
                *(float4*)&sh[8] = *(const float4*)&sr[8];
                #pragma unroll
                for (int o = 0; o < 9; ++o)
                    #pragma unroll
                    for (int j = 0; j < 4; ++j)
                        acc[t][o][j] += cen[j] * sh[o + j];
            }
        }
    }

    // epilogue: per oy -> rowsum (shfl + LDS), colsum, direct + mirror stores
    const float inv = 1.0f / 144.0f;
    float* outb = out + (size_t)b * 81 * HW;
    const int yb  = tid / 6;    // colsum mapping (tid<180): y 0..29
    const int xgb = tid % 6;    // x-group 0..5 (float4)

    #pragma unroll
    for (int t = 0; t < 3; ++t) {
        if (t < NOY) {
            const int oy = oymin + t;
            // unconditional: at t=0 this fences last planes-read vs rsum-write
            // (planes and rsum alias); at t>0 it fences previous colsum reads.
            __syncthreads();
            #pragma unroll
            for (int o = 0; o < 9; ++o) {
                const float a0 = acc[t][o][0], a1 = acc[t][o][1];
                const float a2 = acc[t][o][2], a3 = acc[t][o][3];
                const float left  = __shfl_up(a3, 1);    // (r,g-1) corr at xs-1
                const float right = __shfl_down(a0, 1);  // (r,g+1) corr at xs+4
                if (g >= 1 && g <= 6) {
                    float4 v;
                    v.x = left + a0 + a1;
                    v.y = a0 + a1 + a2;
                    v.z = a1 + a2 + a3;
                    v.w = a2 + a3 + right;
                    *(float4*)&rsum[(o * 32 + r) * RSS + ((g - 1) << 2)] = v;
                }
            }
            __syncthreads();
            if (tid < 180) {
                const int gy = y0 + yb;
                const int gx = x0 + (xgb << 2);
                const bool dok = ((unsigned)gy < HH) && ((unsigned)gx <= (WW - 4));
                const int my = gy + oy;
                #pragma unroll
                for (int o = 0; o < 9; ++o) {
                    const float* rp = &rsum[(o * 32 + yb) * RSS + (xgb << 2)];
                    const float4 s0 = *(const float4*)&rp[0];
                    const float4 s1 = *(const float4*)&rp[RSS];
                    const float4 s2 = *(const float4*)&rp[2 * RSS];
                    float4 s;
                    s.x = (s0.x + s1.x + s2.x) * inv;
                    s.y = (s0.y + s1.y + s2.y) * inv;
                    s.z = (s0.z + s1.z + s2.z) * inv;
                    s.w = (s0.w + s1.w + s2.w) * inv;
                    if (dok)
                        *(float4*)&outb[((size_t)((oy + 4) * 9 + o)) * HW + gy * WW + gx] = s;
                    if (oy < 0 && (unsigned)my < HH) {
                        // mirror: out_{(-oy,-ox)}(gy+oy, gx+j+ox) = s[j]
                        float* mp = &outb[((size_t)((4 - oy) * 9 + (8 - o))) * HW + (size_t)my * WW];
                        const float sv[4] = {s.x, s.y, s.z, s.w};
                        const int mx0 = gx + (o - 4);
                        #pragma unroll
                        for (int j = 0; j < 4; ++j) {
                            const int mx = mx0 + j;
                            if ((unsigned)mx < WW) mp[mx] = sv[j];
                        }
                    }
                }
            }
        }
    }
}

extern "C" void kernel_launch(void* const* d_in, const int* in_sizes, int n_in,
                              void* d_out, int out_size, void* d_ws, size_t ws_size,
                              hipStream_t stream) {
    const float* noise = (const float*)d_in[0];
    float* out = (float*)d_out;
    dim3 grid(9 * 7, 2, 8);   // 9 bx x 7 by extended tiles, 2 oy-groups, 8 batches
    noise_corr_kernel<<<grid, 256, 0, stream>>>(noise, out);
}

// Round 6
// 163.934 us; speedup vs baseline: 2.5708x; 1.0751x over previous
//
#include <hip/hip_runtime.h>

#define HH 192
#define WW 192
#define CC 16
#define HW (HH * WW)
#define TH 30
#define TW 24
#define RS 44               // plane row stride in floats = 11 float4 chunks
#define PCHUNKS 512         // chunks per plane buffer = 256 threads x 2 (ALL DMA'd)
#define PLANEF (PCHUNKS*4)  // 2048 floats per buffer
#define RSS 28              // rowsum row stride floats
#define SMEMF 8192          // floats: max(4*PLANEF=8192, 9*32*RSS=8064) -> 32768 B

// 16B of guaranteed zeros in global memory: OOB lanes DMA from here so the
// global_load_lds is exec-uniform (lane 0 always active -> correct wave base).
__device__ float g_zero16[4] = {0.f, 0.f, 0.f, 0.f};

__device__ __forceinline__ void gload16(const void* g, void* l) {
    __builtin_amdgcn_global_load_lds(
        (const __attribute__((address_space(1))) void*)g,
        (__attribute__((address_space(3))) void*)l, 16, 0, 0);
}

// Block: 256 threads = 32 corr-rows x 8 col-groups(4 cols).
// Each block: one batch, one 30x24 EXTENDED tile, one oy-group
// (grp0 -> oy {-4,-3,-2}, grp1 -> oy {-1,0}); mirror-write oy>0 planes.
//
// launch_bounds stays (256,3): empirical VGPR cap on this toolchain is 256/w
// (w=3 -> 84 regs, no spill; w=4 -> 64 regs -> scratch spill, 2x slower).
// 84 regs <= 128 -> HW grants 4 waves/SIMD anyway; with 32 KB LDS -> 4
// blocks/CU (131072 <= 163840), capacity 1024 >= 1008-block grid, one round.
//
// DMA pipeline: QUAD-buffered global_load_lds, prefetch distance 3 (~1100 cyc
// of compute cover > ~900 cyc HBM-miss latency; distance 2's ~750 cyc only
// covered L2 hits). Counted s_waitcnt vmcnt(4) steady state -- never 0 until
// the tail. Raw s_barrier (no compiler vmcnt(0) drain).
//
// LDS: single 32 KB buffer, time-aliased:
//   main loop -> planes[4*PLANEF] (32 KB quad-buffered DMA dest)
//   epilogue  -> rsum[9*32*RSS]   (31.5 KB)
__global__ __launch_bounds__(256, 3)
void noise_corr_kernel(const float* __restrict__ noise, float* __restrict__ out) {
    __shared__ float smem[SMEMF];
    float* const planes = smem;            // alias: valid until last channel compute
    float* const rsum   = smem;            // alias: valid after epilogue barrier

    const int tid = threadIdx.x;
    const int r   = tid >> 3;          // 0..31 -> corr row yy = r-1
    const int g   = tid & 7;           // 0..7  -> cols xs = 4g-4
    const int bx  = blockIdx.x % 9;
    const int by  = blockIdx.x / 9;
    const int grp = blockIdx.y;
    const int b   = blockIdx.z;

    const int oymin = grp ? -1 : -4;
    const int NOY   = grp ? 2 : 3;
    const int rmin  = oymin - 1;
    const int NR    = TH + 2 - oymin;  // 36 (grp0) / 33 (grp1)
    const int nitems = NR * 11;        // used float4 chunks (<= 512)

    const int y0 = -4 + by * TH;       // extended tile origin
    const int x0 = -4 + bx * TW;
    const int yy = r - 1;
    const int xs = (g << 2) - 4;

    const float* nb = noise + (size_t)b * CC * HW;
    const char* zp = (const char*)g_zero16;

    // precompute this thread's 2 staging chunks (plane offset = 16*i, linear in tid)
    int goff[2]; bool gok[2];
    #pragma unroll
    for (int k = 0; k < 2; ++k) {
        const int i  = tid + (k << 8);
        const int rr = i / 11;
        const int q  = i - rr * 11;
        const int gy = y0 + rmin + rr;
        const int gx = x0 - 8 + (q << 2);   // 4-aligned -> chunk fully in or out
        gok[k]  = (i < nitems) && ((unsigned)gy < HH) && ((unsigned)gx <= (WW - 4));
        goff[k] = (gy * WW + gx) * 4;
    }

    float acc[3][9][4];
    #pragma unroll
    for (int t = 0; t < 3; ++t)
        #pragma unroll
        for (int o = 0; o < 9; ++o) {
            acc[t][o][0] = 0.f; acc[t][o][1] = 0.f;
            acc[t][o][2] = 0.f; acc[t][o][3] = 0.f;
        }

    // prologue: stage channels 0,1,2 into slots 0,1,2 (6 loads in flight)
    #pragma unroll
    for (int p = 0; p < 3; ++p) {
        const char* base = (const char*)(nb + (size_t)p * HW);
        char* lb = (char*)planes + p * (PLANEF * 4);
        gload16(gok[0] ? base + goff[0] : zp, lb + (tid << 4));
        gload16(gok[1] ? base + goff[1] : zp, lb + ((tid + 256) << 4));
    }

    const int ci = yy - rmin;   // center row in plane; shifted row = ci + oy

    for (int c = 0; c < CC; ++c) {
        // wait for THIS wave's slot-c loads only (newer prefetches stay in
        // flight), then raw barrier (no compiler vmcnt(0) drain).
        if (c == CC - 1) {
            asm volatile("s_waitcnt vmcnt(0)" ::: "memory");
        } else if (c == CC - 2) {
            asm volatile("s_waitcnt vmcnt(2)" ::: "memory");
        } else {
            asm volatile("s_waitcnt vmcnt(4)" ::: "memory");
        }
        __builtin_amdgcn_sched_barrier(0);   // rule #18: pin reads below the wait
        __builtin_amdgcn_s_barrier();
        // issue slot c+3: its previous readers (compute c-1) all passed the
        // barrier above, so the DMA write cannot race them.
        if (c + 3 < CC) {
            const char* base = (const char*)(nb + (size_t)(c + 3) * HW);
            char* lb = (char*)planes + ((c + 3) & 3) * (PLANEF * 4);
            gload16(gok[0] ? base + goff[0] : zp, lb + (tid << 4));
            gload16(gok[1] ? base + goff[1] : zp, lb + ((tid + 256) << 4));
        }
        const float* pl = planes + (c & 3) * PLANEF;
        const float4 cen4 = *(const float4*)&pl[ci * RS + xs + 8];
        const float cen[4] = {cen4.x, cen4.y, cen4.z, cen4.w};
        #pragma unroll
        for (int t = 0; t < 3; ++t) {
            if (t < NOY) {
                const float* sr = &pl[(ci + oymin + t) * RS + xs + 4];
                float sh[12];
                *(float4*)&sh[0] = *(const float4*)&sr[0];
                *(float4*)&sh[4] = *(const float4*)&sr[4];
                *(float4*)&sh[8] = *(const float4*)&sr[8];
                #pragma unroll
                for (int o = 0; o < 9; ++o)
                    #pragma unroll
                    for (int j = 0; j < 4; ++j)
                        acc[t][o][j] += cen[j] * sh[o + j];
            }
        }
    }

    // epilogue: per oy -> rowsum (shfl + LDS), colsum, direct + mirror stores
    const float inv = 1.0f / 144.0f;
    float* outb = out + (size_t)b * 81 * HW;
    const int yb  = tid / 6;    // colsum mapping (tid<180): y 0..29
    const int xgb = tid % 6;    // x-group 0..5 (float4)

    #pragma unroll
    for (int t = 0; t < 3; ++t) {
        if (t < NOY) {
            const int oy = oymin + t;
            // unconditional: at t=0 this fences last planes-read vs rsum-write
            // (planes and rsum alias); at t>0 it fences previous colsum reads.
            __syncthreads();
            #pragma unroll
            for (int o = 0; o < 9; ++o) {
                const float a0 = acc[t][o][0], a1 = acc[t][o][1];
                const float a2 = acc[t][o][2], a3 = acc[t][o][3];
                const float left  = __shfl_up(a3, 1);    // (r,g-1) corr at xs-1
                const float right = __shfl_down(a0, 1);  // (r,g+1) corr at xs+4
                if (g >= 1 && g <= 6) {
                    float4 v;
                    v.x = left + a0 + a1;
                    v.y = a0 + a1 + a2;
                    v.z = a1 + a2 + a3;
                    v.w = a2 + a3 + right;
                    *(float4*)&rsum[(o * 32 + r) * RSS + ((g - 1) << 2)] = v;
                }
            }
            __syncthreads();
            if (tid < 180) {
                const int gy = y0 + yb;
                const int gx = x0 + (xgb << 2);
                const bool dok = ((unsigned)gy < HH) && ((unsigned)gx <= (WW - 4));
                const int my = gy + oy;
                #pragma unroll
                for (int o = 0; o < 9; ++o) {
                    const float* rp = &rsum[(o * 32 + yb) * RSS + (xgb << 2)];
                    const float4 s0 = *(const float4*)&rp[0];
                    const float4 s1 = *(const float4*)&rp[RSS];
                    const float4 s2 = *(const float4*)&rp[2 * RSS];
                    float4 s;
                    s.x = (s0.x + s1.x + s2.x) * inv;
                    s.y = (s0.y + s1.y + s2.y) * inv;
                    s.z = (s0.z + s1.z + s2.z) * inv;
                    s.w = (s0.w + s1.w + s2.w) * inv;
                    if (dok)
                        *(float4*)&outb[((size_t)((oy + 4) * 9 + o)) * HW + gy * WW + gx] = s;
                    if (oy < 0 && (unsigned)my < HH) {
                        // mirror: out_{(-oy,-ox)}(gy+oy, gx+j+ox) = s[j]
                        float* mp = &outb[((size_t)((4 - oy) * 9 + (8 - o))) * HW + (size_t)my * WW];
                        const float sv[4] = {s.x, s.y, s.z, s.w};
                        const int mx0 = gx + (o - 4);
                        #pragma unroll
                        for (int j = 0; j < 4; ++j) {
                            const int mx = mx0 + j;
                            if ((unsigned)mx < WW) mp[mx] = sv[j];
                        }
                    }
                }
            }
        }
    }
}

extern "C" void kernel_launch(void* const* d_in, const int* in_sizes, int n_in,
                              void* d_out, int out_size, void* d_ws, size_t ws_size,
                              hipStream_t stream) {
    const float* noise = (const float*)d_in[0];
    float* out = (float*)d_out;
    dim3 grid(9 * 7, 2, 8);   // 9 bx x 7 by extended tiles, 2 oy-groups, 8 batches
    noise_corr_kernel<<<grid, 256, 0, stream>>>(noise, out);
}

// Round 7
// 161.693 us; speedup vs baseline: 2.6064x; 1.0139x over previous
//
#include <hip/hip_runtime.h>

#define HH 192
#define WW 192
#define CC 16
#define HW (HH * WW)
#define TH 30
#define TW 24
#define RSW 44              // slot row stride floats = 11 float4 chunks
#define SLOTB 3072          // bytes per slot = 192 chunks (3 gload16 x 64 lanes)
#define WSTRB (3 * SLOTB)   // 9216 B per wave (3 slots, triple buffer)
#define RSS 28              // rowsum row stride floats
#define SMEMF 9216          // floats = 36864 B = 4 waves * WSTRB (>= rsum 8064)

// 16B of guaranteed zeros in global memory: OOB lanes DMA from here so the
// global_load_lds is exec-uniform (lane 0 always active -> correct wave base).
__device__ float g_zero16[4] = {0.f, 0.f, 0.f, 0.f};

__device__ __forceinline__ void gload16(const void* g, void* l) {
    __builtin_amdgcn_global_load_lds(
        (const __attribute__((address_space(1))) void*)g,
        (__attribute__((address_space(3))) void*)l, 16, 0, 0);
}

// Block: 256 threads = 32 corr-rows x 8 col-groups(4 cols); wave w owns corr
// rows r in [8w, 8w+8). Each block: one batch, one 30x24 EXTENDED tile, one
// oy-group (grp0 -> oy {-4,-3,-2}, grp1 -> oy {-1,0}); mirror-write oy>0.
//
// WAVE-PRIVATE STAGING (this round's change): each wave DMAs the 12 rows
// (grp0; 9 for grp1) that IT reads into its own triple-buffered LDS slots and
// self-paces with counted vmcnt only -- ZERO s_barrier in the main loop.
// Rationale: r0-r6 showed every pipe <=22% busy and occupancy/pipeline levers
// null; the block-lockstep barrier cadence (14k cyc/channel vs ~400 cyc work)
// is the remaining structural serializer. Slot-reuse WAR is safe: slot X's
// ds_reads are consumed by channel c-1's FMAs (lgkm-drained by data dep)
// before this wave issues the next DMA targeting X at channel c.
//
// launch_bounds stays (256,3): total reg budget 512/w (VGPR+AGPR-side);
// w=3 -> ~170 total, fits acc[3][9][4]=108 + staging state; w>=4 spills
// (r2/r3: 300MB-1.1GB scratch traffic). 3 waves/SIMD, 3 blocks/CU.
//
// LDS: 36864 B, time-aliased: main loop -> 4 waves x 3 slots x 3072 B;
// epilogue -> rsum[9*32*RSS] (31.5 KB). Epilogue __syncthreads fences alias.
__global__ __launch_bounds__(256, 3)
void noise_corr_kernel(const float* __restrict__ noise, float* __restrict__ out) {
    __shared__ float smem[SMEMF];
    float* const rsum = smem;          // alias: valid after epilogue barrier

    const int tid  = threadIdx.x;
    const int w    = tid >> 6;         // wave 0..3
    const int lane = tid & 63;
    const int r    = tid >> 3;         // 0..31 -> corr row yy = r-1
    const int g    = tid & 7;          // 0..7  -> cols xs = 4g-4
    const int lr   = lane >> 3;        // 0..7, r = 8w + lr
    const int bx   = blockIdx.x % 9;
    const int by   = blockIdx.x / 9;
    const int grp  = blockIdx.y;
    const int b    = blockIdx.z;

    const int oymin = grp ? -1 : -4;
    const int NOY   = grp ? 2 : 3;
    const int rmin  = oymin - 1;
    const int NRW   = grp ? 9 : 12;    // rows staged per wave
    const int KL    = grp ? 2 : 3;     // gload16 per channel per wave

    const int y0 = -4 + by * TH;       // extended tile origin
    const int x0 = -4 + bx * TW;
    const int xs = (g << 2) - 4;

    const float* nb = noise + (size_t)b * CC * HW;
    const char* zp  = (const char*)g_zero16;
    char* const wb  = (char*)smem + w * WSTRB;   // this wave's LDS region

    // wave's staged band: global row gy = wrow0 + rr_local, rr_local in [0,NRW)
    const int wrow0 = y0 + rmin + (w << 3);

    // per-lane staging chunks: instr k covers chunks i = 64k + lane
    int goff[3]; bool gok[3];
    #pragma unroll
    for (int k = 0; k < 3; ++k) {
        const int i  = (k << 6) + lane;
        const int rr = i / 11;
        const int q  = i - rr * 11;
        const int gy = wrow0 + rr;
        const int gx = x0 - 8 + (q << 2);   // 4-aligned -> chunk fully in or out
        gok[k]  = (i < NRW * 11) && ((unsigned)gy < HH) && ((unsigned)gx <= (WW - 4));
        goff[k] = (gy * WW + gx) * 4;
    }

    float acc[3][9][4];
    #pragma unroll
    for (int t = 0; t < 3; ++t)
        #pragma unroll
        for (int o = 0; o < 9; ++o) {
            acc[t][o][0] = 0.f; acc[t][o][1] = 0.f;
            acc[t][o][2] = 0.f; acc[t][o][3] = 0.f;
        }

    // prologue: slots 0,1 <- channels 0,1 (2*KL loads in flight per wave)
    #pragma unroll
    for (int p = 0; p < 2; ++p) {
        const char* base = (const char*)(nb + (size_t)p * HW);
        char* lb = wb + p * SLOTB;
        #pragma unroll
        for (int k = 0; k < 3; ++k)
            if (k < KL)
                gload16(gok[k] ? base + goff[k] : zp, lb + (((k << 6) + lane) << 4));
    }

    // center row in wave-local slot coords; shifted row = ci_l + oymin + t
    const int ci_l = lr - 1 - rmin;    // grp0: lr+4 (<12), grp1: lr+1 (<9)

    int scur = 0, spre = 2;            // slot(c), slot(c+2) mod 3
    for (int c = 0; c < CC; ++c) {
        // issue channel c+2 into slot spre FIRST (never blocked by the wait);
        // spre's previous readers were channel c-1's FMAs -> already drained.
        if (c + 2 < CC) {
            const char* base = (const char*)(nb + (size_t)(c + 2) * HW);
            char* lb = wb + spre * SLOTB;
            #pragma unroll
            for (int k = 0; k < 3; ++k)
                if (k < KL)
                    gload16(gok[k] ? base + goff[k] : zp, lb + (((k << 6) + lane) << 4));
        }
        // counted per-wave wait: drain slot c, keep 2 newer slots in flight.
        if (c < CC - 2) {
            if (grp) asm volatile("s_waitcnt vmcnt(4)" ::: "memory");
            else     asm volatile("s_waitcnt vmcnt(6)" ::: "memory");
        } else if (c == CC - 2) {
            if (grp) asm volatile("s_waitcnt vmcnt(2)" ::: "memory");
            else     asm volatile("s_waitcnt vmcnt(3)" ::: "memory");
        } else {
            asm volatile("s_waitcnt vmcnt(0)" ::: "memory");
        }
        __builtin_amdgcn_sched_barrier(0);   // pin slot-c reads below the wait

        const float* pl = (const float*)(wb + scur * SLOTB);
        const float4 cen4 = *(const float4*)&pl[ci_l * RSW + xs + 8];
        const float cen[4] = {cen4.x, cen4.y, cen4.z, cen4.w};
        #pragma unroll
        for (int t = 0; t < 3; ++t) {
            if (t < NOY) {
                const float* sr = &pl[(ci_l + oymin + t) * RSW + xs + 4];
                float sh[12];
                *(float4*)&sh[0] = *(const float4*)&sr[0];
                *(float4*)&sh[4] = *(const float4*)&sr[4];
                *(float4*)&sh[8] = *(const float4*)&sr[8];
                #pragma unroll
                for (int o = 0; o < 9; ++o)
                    #pragma unroll
                    for (int j = 0; j < 4; ++j)
                        acc[t][o][j] += cen[j] * sh[o + j];
            }
        }
        scur = (scur == 2) ? 0 : scur + 1;
        spre = (spre == 2) ? 0 : spre + 1;
    }

    // epilogue: per oy -> rowsum (shfl + LDS), colsum, direct + mirror stores
    const float inv = 1.0f / 144.0f;
    float* outb = out + (size_t)b * 81 * HW;
    const int yb  = tid / 6;    // colsum mapping (tid<180): y 0..29
    const int xgb = tid % 6;    // x-group 0..5 (float4)

    #pragma unroll
    for (int t = 0; t < 3; ++t) {
        if (t < NOY) {
            const int oy = oymin + t;
            // unconditional: at t=0 this fences all waves' main-loop slot reads
            // vs rsum writes (alias); at t>0 it fences previous colsum reads.
            __syncthreads();
            #pragma unroll
            for (int o = 0; o < 9; ++o) {
                const float a0 = acc[t][o][0], a1 = acc[t][o][1];
                const float a2 = acc[t][o][2], a3 = acc[t][o][3];
                const float left  = __shfl_up(a3, 1);    // (r,g-1) corr at xs-1
                const float right = __shfl_down(a0, 1);  // (r,g+1) corr at xs+4
                if (g >= 1 && g <= 6) {
                    float4 v;
                    v.x = left + a0 + a1;
                    v.y = a0 + a1 + a2;
                    v.z = a1 + a2 + a3;
                    v.w = a2 + a3 + right;
                    *(float4*)&rsum[(o * 32 + r) * RSS + ((g - 1) << 2)] = v;
                }
            }
            __syncthreads();
            if (tid < 180) {
                const int gy = y0 + yb;
                const int gx = x0 + (xgb << 2);
                const bool dok = ((unsigned)gy < HH) && ((unsigned)gx <= (WW - 4));
                const int my = gy + oy;
                #pragma unroll
                for (int o = 0; o < 9; ++o) {
                    const float* rp = &rsum[(o * 32 + yb) * RSS + (xgb << 2)];
                    const float4 s0 = *(const float4*)&rp[0];
                    const float4 s1 = *(const float4*)&rp[RSS];
                    const float4 s2 = *(const float4*)&rp[2 * RSS];
                    float4 s;
                    s.x = (s0.x + s1.x + s2.x) * inv;
                    s.y = (s0.y + s1.y + s2.y) * inv;
                    s.z = (s0.z + s1.z + s2.z) * inv;
                    s.w = (s0.w + s1.w + s2.w) * inv;
                    if (dok)
                        *(float4*)&outb[((size_t)((oy + 4) * 9 + o)) * HW + gy * WW + gx] = s;
                    if (oy < 0 && (unsigned)my < HH) {
                        // mirror: out_{(-oy,-ox)}(gy+oy, gx+j+ox) = s[j]
                        float* mp = &outb[((size_t)((4 - oy) * 9 + (8 - o))) * HW + (size_t)my * WW];
                        const float sv[4] = {s.x, s.y, s.z, s.w};
                        const int mx0 = gx + (o - 4);
                        #pragma unroll
                        for (int j = 0; j < 4; ++j) {
                            const int mx = mx0 + j;
                            if ((unsigned)mx < WW) mp[mx] = sv[j];
                        }
                    }
                }
            }
        }
    }
}

extern "C" void kernel_launch(void* const* d_in, const int* in_sizes, int n_in,
                              void* d_out, int out_size, void* d_ws, size_t ws_size,
                              hipStream_t stream) {
    const float* noise = (const float*)d_in[0];
    float* out = (float*)d_out;
    dim3 grid(9 * 7, 2, 8);   // 9 bx x 7 by extended tiles, 2 oy-groups, 8 batches
    noise_corr_kernel<<<grid, 256, 0, stream>>>(noise, out);
}

// Round 8
// 152.450 us; speedup vs baseline: 2.7644x; 1.0606x over previous
//
#include <hip/hip_runtime.h>

#define HH 192
#define WW 192
#define CC 16
#define HW (HH * WW)
#define TH 30
#define TW 24
#define RSW 44              // slot row stride floats = 11 float4 chunks
#define SLOTB 3072          // bytes per slot = 192 chunks (3 gload16 x 64 lanes)
#define WSTRB (3 * SLOTB)   // 9216 B per wave (3 slots, triple buffer)
#define RSS 28              // rowsum row stride floats
#define SMEMF 9216          // floats = 36864 B = 4 waves * WSTRB (>= rsum 8064)

// 16B of guaranteed zeros in global memory: OOB lanes DMA from here so the
// global_load_lds is exec-uniform (lane 0 always active -> correct wave base).
__device__ float g_zero16[4] = {0.f, 0.f, 0.f, 0.f};

__device__ __forceinline__ void gload16(const void* g, void* l) {
    __builtin_amdgcn_global_load_lds(
        (const __attribute__((address_space(1))) void*)g,
        (__attribute__((address_space(3))) void*)l, 16, 0, 0);
}

// Block: 256 threads = 32 corr-rows x 8 col-groups(4 cols); wave w owns corr
// rows r in [8w, 8w+8). Each block: one batch, one 30x24 EXTENDED tile, one
// oy-group (grp0 -> oy {-4,-3,-2}, grp1 -> oy {-1,0}); mirror-write oy>0.
//
// XCD-BATCH SWIZZLE (this round's change): 1D grid of 1008; HW assigns
// workgroups to the 8 XCDs round-robin (n % 8), so decoding batch = n & 7
// gives each XCD exactly ONE batch's 126 blocks (1008 % 8 == 0, bijective).
// Per channel-step an XCD then streams one 2.3 MB plane (fits 4 MB L2)
// instead of 8 batches x 2.3 MB (thrash). r7 evidence: FETCH_SIZE = 39 MB =
// 2x input -> input fetched twice from HBM; all pipes <= 25% busy -> the
// stall is congested DMA-miss latency, invisible to busy counters.
//
// WAVE-PRIVATE STAGING (r7): each wave DMAs the 12 rows (grp0; 9 grp1) that
// IT reads into its own triple-buffered LDS slots, self-paced by counted
// vmcnt only -- zero s_barrier in the main loop. Slot-reuse WAR safe: slot
// X's ds_reads are consumed by channel c-1's FMAs before the next DMA to X.
//
// launch_bounds stays (256,3): empirical toolchain law cap = 256/w
// (w=3 -> 84 regs, no spill; w>=4 spills catastrophically, r2/r3).
// 84 regs -> <=128 tier -> 4 waves/SIMD; LDS 36.9 KB -> 4 blocks/CU.
//
// LDS: 36864 B, time-aliased: main loop -> 4 waves x 3 slots x 3072 B;
// epilogue -> rsum[9*32*RSS] (31.5 KB). Epilogue __syncthreads fences alias.
__global__ __launch_bounds__(256, 3)
void noise_corr_kernel(const float* __restrict__ noise, float* __restrict__ out) {
    __shared__ float smem[SMEMF];
    float* const rsum = smem;          // alias: valid after epilogue barrier

    const int tid  = threadIdx.x;
    const int w    = tid >> 6;         // wave 0..3
    const int lane = tid & 63;
    const int r    = tid >> 3;         // 0..31 -> corr row yy = r-1
    const int g    = tid & 7;          // 0..7  -> cols xs = 4g-4
    // XCD-batch swizzle decode: n%8 = XCD = batch; n>>3 = 126 tile/grp combos
    const int n    = blockIdx.x;
    const int b    = n & 7;
    const int m    = n >> 3;           // 0..125
    const int grp  = (m >= 63) ? 1 : 0;
    const int tile = grp ? (m - 63) : m;
    const int bx   = tile % 9;
    const int by   = tile / 9;
    const int lr   = lane >> 3;        // 0..7, r = 8w + lr

    const int oymin = grp ? -1 : -4;
    const int NOY   = grp ? 2 : 3;
    const int rmin  = oymin - 1;
    const int NRW   = grp ? 9 : 12;    // rows staged per wave
    const int KL    = grp ? 2 : 3;     // gload16 per channel per wave

    const int y0 = -4 + by * TH;       // extended tile origin
    const int x0 = -4 + bx * TW;
    const int xs = (g << 2) - 4;

    const float* nb = noise + (size_t)b * CC * HW;
    const char* zp  = (const char*)g_zero16;
    char* const wb  = (char*)smem + w * WSTRB;   // this wave's LDS region

    // wave's staged band: global row gy = wrow0 + rr_local, rr_local in [0,NRW)
    const int wrow0 = y0 + rmin + (w << 3);

    // per-lane staging chunks: instr k covers chunks i = 64k + lane
    int goff[3]; bool gok[3];
    #pragma unroll
    for (int k = 0; k < 3; ++k) {
        const int i  = (k << 6) + lane;
        const int rr = i / 11;
        const int q  = i - rr * 11;
        const int gy = wrow0 + rr;
        const int gx = x0 - 8 + (q << 2);   // 4-aligned -> chunk fully in or out
        gok[k]  = (i < NRW * 11) && ((unsigned)gy < HH) && ((unsigned)gx <= (WW - 4));
        goff[k] = (gy * WW + gx) * 4;
    }

    float acc[3][9][4];
    #pragma unroll
    for (int t = 0; t < 3; ++t)
        #pragma unroll
        for (int o = 0; o < 9; ++o) {
            acc[t][o][0] = 0.f; acc[t][o][1] = 0.f;
            acc[t][o][2] = 0.f; acc[t][o][3] = 0.f;
        }

    // prologue: slots 0,1 <- channels 0,1 (2*KL loads in flight per wave)
    #pragma unroll
    for (int p = 0; p < 2; ++p) {
        const char* base = (const char*)(nb + (size_t)p * HW);
        char* lb = wb + p * SLOTB;
        #pragma unroll
        for (int k = 0; k < 3; ++k)
            if (k < KL)
                gload16(gok[k] ? base + goff[k] : zp, lb + (((k << 6) + lane) << 4));
    }

    // center row in wave-local slot coords; shifted row = ci_l + oymin + t
    const int ci_l = lr - 1 - rmin;    // grp0: lr+4 (<12), grp1: lr+1 (<9)

    int scur = 0, spre = 2;            // slot(c), slot(c+2) mod 3
    for (int c = 0; c < CC; ++c) {
        // issue channel c+2 into slot spre FIRST (never blocked by the wait);
        // spre's previous readers were channel c-1's FMAs -> already drained.
        if (c + 2 < CC) {
            const char* base = (const char*)(nb + (size_t)(c + 2) * HW);
            char* lb = wb + spre * SLOTB;
            #pragma unroll
            for (int k = 0; k < 3; ++k)
                if (k < KL)
                    gload16(gok[k] ? base + goff[k] : zp, lb + (((k << 6) + lane) << 4));
        }
        // counted per-wave wait: drain slot c, keep 2 newer slots in flight.
        if (c < CC - 2) {
            if (grp) asm volatile("s_waitcnt vmcnt(4)" ::: "memory");
            else     asm volatile("s_waitcnt vmcnt(6)" ::: "memory");
        } else if (c == CC - 2) {
            if (grp) asm volatile("s_waitcnt vmcnt(2)" ::: "memory");
            else     asm volatile("s_waitcnt vmcnt(3)" ::: "memory");
        } else {
            asm volatile("s_waitcnt vmcnt(0)" ::: "memory");
        }
        __builtin_amdgcn_sched_barrier(0);   // pin slot-c reads below the wait

        const float* pl = (const float*)(wb + scur * SLOTB);
        const float4 cen4 = *(const float4*)&pl[ci_l * RSW + xs + 8];
        const float cen[4] = {cen4.x, cen4.y, cen4.z, cen4.w};
        #pragma unroll
        for (int t = 0; t < 3; ++t) {
            if (t < NOY) {
                const float* sr = &pl[(ci_l + oymin + t) * RSW + xs + 4];
                float sh[12];
                *(float4*)&sh[0] = *(const float4*)&sr[0];
                *(float4*)&sh[4] = *(const float4*)&sr[4];
                *(float4*)&sh[8] = *(const float4*)&sr[8];
                #pragma unroll
                for (int o = 0; o < 9; ++o)
                    #pragma unroll
                    for (int j = 0; j < 4; ++j)
                        acc[t][o][j] += cen[j] * sh[o + j];
            }
        }
        scur = (scur == 2) ? 0 : scur + 1;
        spre = (spre == 2) ? 0 : spre + 1;
    }

    // epilogue: per oy -> rowsum (shfl + LDS), colsum, direct + mirror stores
    const float inv = 1.0f / 144.0f;
    float* outb = out + (size_t)b * 81 * HW;
    const int yb  = tid / 6;    // colsum mapping (tid<180): y 0..29
    const int xgb = tid % 6;    // x-group 0..5 (float4)

    #pragma unroll
    for (int t = 0; t < 3; ++t) {
        if (t < NOY) {
            const int oy = oymin + t;
            // unconditional: at t=0 this fences all waves' main-loop slot reads
            // vs rsum writes (alias); at t>0 it fences previous colsum reads.
            __syncthreads();
            #pragma unroll
            for (int o = 0; o < 9; ++o) {
                const float a0 = acc[t][o][0], a1 = acc[t][o][1];
                const float a2 = acc[t][o][2], a3 = acc[t][o][3];
                const float left  = __shfl_up(a3, 1);    // (r,g-1) corr at xs-1
                const float right = __shfl_down(a0, 1);  // (r,g+1) corr at xs+4
                if (g >= 1 && g <= 6) {
                    float4 v;
                    v.x = left + a0 + a1;
                    v.y = a0 + a1 + a2;
                    v.z = a1 + a2 + a3;
                    v.w = a2 + a3 + right;
                    *(float4*)&rsum[(o * 32 + r) * RSS + ((g - 1) << 2)] = v;
                }
            }
            __syncthreads();
            if (tid < 180) {
                const int gy = y0 + yb;
                const int gx = x0 + (xgb << 2);
                const bool dok = ((unsigned)gy < HH) && ((unsigned)gx <= (WW - 4));
                const int my = gy + oy;
                #pragma unroll
                for (int o = 0; o < 9; ++o) {
                    const float* rp = &rsum[(o * 32 + yb) * RSS + (xgb << 2)];
                    const float4 s0 = *(const float4*)&rp[0];
                    const float4 s1 = *(const float4*)&rp[RSS];
                    const float4 s2 = *(const float4*)&rp[2 * RSS];
                    float4 s;
                    s.x = (s0.x + s1.x + s2.x) * inv;
                    s.y = (s0.y + s1.y + s2.y) * inv;
                    s.z = (s0.z + s1.z + s2.z) * inv;
                    s.w = (s0.w + s1.w + s2.w) * inv;
                    if (dok)
                        *(float4*)&outb[((size_t)((oy + 4) * 9 + o)) * HW + gy * WW + gx] = s;
                    if (oy < 0 && (unsigned)my < HH) {
                        // mirror: out_{(-oy,-ox)}(gy+oy, gx+j+ox) = s[j]
                        float* mp = &outb[((size_t)((4 - oy) * 9 + (8 - o))) * HW + (size_t)my * WW];
                        const float sv[4] = {s.x, s.y, s.z, s.w};
                        const int mx0 = gx + (o - 4);
                        #pragma unroll
                        for (int j = 0; j < 4; ++j) {
                            const int mx = mx0 + j;
                            if ((unsigned)mx < WW) mp[mx] = sv[j];
                        }
                    }
                }
            }
        }
    }
}

extern "C" void kernel_launch(void* const* d_in, const int* in_sizes, int n_in,
                              void* d_out, int out_size, void* d_ws, size_t ws_size,
                              hipStream_t stream) {
    const float* noise = (const float*)d_in[0];
    float* out = (float*)d_out;
    // 1D grid: linear id n -> XCD = n%8 (HW round-robin) = batch (n&7).
    // 1008 = 126 * 8 -> bijective batch-aligned XCD swizzle.
    dim3 grid(9 * 7 * 2 * 8, 1, 1);
    noise_corr_kernel<<<grid, 256, 0, stream>>>(noise, out);
}